// Round 12
// baseline (33.723 us; speedup 1.0000x reference)
//
#include <hip/hip_runtime.h>
#include <stdint.h>

// Problem constants
constexpr int Dn = 10000;
constexpr int Bn = 128;
constexpr int Wn = 512;
constexpr int Hn = 128;
constexpr int NTILES = 157;      // d-tiles of N=64 (157*64 = 10048 >= 10000)
constexpr int NTD = 625;         // d-subtiles of 16 (b-fragment granularity)

typedef float  f32x4  __attribute__((ext_vector_type(4)));
typedef short  bf16x8 __attribute__((ext_vector_type(8)));  // 8 bf16 (4 VGPRs)

__device__ inline uint16_t f32_to_bf16(float f) {           // RNE
    uint32_t u = __builtin_bit_cast(uint32_t, f);
    return (uint16_t)((u + 0x7FFFu + ((u >> 16) & 1u)) >> 16);
}
__device__ inline float bf16_to_f32(uint16_t h) {
    uint32_t u = ((uint32_t)h) << 16;
    return __builtin_bit_cast(float, u);
}

// ---------------------------------------------------------------------------
// Kernel 1 (fused pre-pass):
//  blocks 0..511  : h-reduction -> sT64[b][w] + aHi/aLo (MFMA A-fragment
//                   layout, bf16 hi/lo split). Identical to R9/R11 (proven).
//  blocks 512..1136: per (g,d): pack sign word bitsT[d*16+g] (for the exact
//                   fixup) AND emit the B-operand bf16 fragments bF:
//                   element (w,d) -> frag (g*625+td), lane (d&15)|(q<<4),
//                   elem j, with g=w>>5, q=(w>>3)&3, j=w&7 -- exactly the
//                   (lane,elem)->k map the gemm's bit-synthesis used (verified
//                   absmax 0), so correctness transfers.
// ---------------------------------------------------------------------------
__global__ __launch_bounds__(256) void prep(const float* __restrict__ x,
                                            const float* __restrict__ wts,
                                            double* __restrict__ sT64,
                                            uint16_t* __restrict__ aHi,
                                            uint16_t* __restrict__ aLo,
                                            uint32_t* __restrict__ bitsT,
                                            uint16_t* __restrict__ bF) {
    int bid = blockIdx.x;
    if (bid < 512) {
        int b  = bid >> 2;
        int w0 = (bid & 3) << 7;            // w-quarter base
        int wc = threadIdx.x & 31;          // float4 column: w = w0 + wc*4
        int hs = threadIdx.x >> 5;          // 8 h-slices of 16
        const f32x4* p = (const f32x4*)(x + (size_t)b * (Hn * Wn)
                                          + (size_t)(hs * 16) * Wn + w0) + wc;
        double a0 = 0, a1 = 0, a2 = 0, a3 = 0;
        #pragma unroll
        for (int h = 0; h < 16; ++h) {
            f32x4 f = p[(size_t)h * (Wn / 4)];
            a0 += (double)f.x; a1 += (double)f.y;
            a2 += (double)f.z; a3 += (double)f.w;
        }
        __shared__ double red[8][128];
        red[hs][wc * 4 + 0] = a0;
        red[hs][wc * 4 + 1] = a1;
        red[hs][wc * 4 + 2] = a2;
        red[hs][wc * 4 + 3] = a3;
        __syncthreads();
        if (threadIdx.x < 128) {
            int wl = threadIdx.x;
            double s = 0.0;
            #pragma unroll
            for (int k = 0; k < 8; ++k) s += red[k][wl];   // fixed order
            int w = w0 + wl;
            sT64[(size_t)b * Wn + w] = s;
            float s32 = (float)s;
            uint16_t hi = f32_to_bf16(s32);
            float hif = bf16_to_f32(hi);
            uint16_t lo = f32_to_bf16(s32 - hif);          // residual capture
            int ktile = w >> 5;
            int mtile = b >> 4;
            int lane  = (b & 15) | (((w >> 3) & 3) << 4);
            int j     = w & 7;
            size_t idx = (size_t)((ktile * 8 + mtile) * 64 + lane) * 8 + j;
            aHi[idx] = hi;
            aLo[idx] = lo;
        }
    } else {
        int idx = (bid - 512) * 256 + (int)threadIdx.x;    // 0 .. 159999 exactly
        int g = idx / Dn;
        int d = idx - g * Dn;
        uint32_t m = 0;
        uint32_t pk[16];                                   // 32 bf16 packed
        #pragma unroll
        for (int q = 0; q < 4; ++q) {
            #pragma unroll
            for (int jp = 0; jp < 4; ++jp) {               // j pairs
                int w = g * 32 + q * 8 + jp * 2;
                uint32_t v0 = (wts[(size_t)w * Dn + d]       > 0.0f) ? 0x3F80u : 0xBF80u;
                uint32_t v1 = (wts[(size_t)(w + 1) * Dn + d] > 0.0f) ? 0x3F80u : 0xBF80u;
                pk[q * 4 + jp] = v0 | (v1 << 16);
                m |= (v0 == 0x3F80u ? 1u : 0u) << (q * 8 + jp * 2);
                m |= (v1 == 0x3F80u ? 1u : 0u) << (q * 8 + jp * 2 + 1);
            }
        }
        bitsT[(size_t)d * 16 + g] = m;
        int td = d >> 4;
        // chunk base (bf16 elems): (g*625+td)*512 + q*128 + (d&15)*8
        uint4* dst = (uint4*)(bF + (size_t)(g * NTD + td) * 512 + ((d & 15) << 3));
        #pragma unroll
        for (int q = 0; q < 4; ++q) {
            uint4 u; u.x = pk[q*4+0]; u.y = pk[q*4+1]; u.z = pk[q*4+2]; u.w = pk[q*4+3];
            dst[q * 16] = u;                               // +q*256 bf16 = +q*16 uint4
        }
    }
}

// ---------------------------------------------------------------------------
// Kernel 2: MFMA GEMM, pure load+MFMA inner loop (no bit synthesis).
// grid (157, 8), 256 threads = 4 waves. Block stages its mt's 32 KB A-slice
// in LDS (as R11); wave w owns the nt=w 16-d slice of d-tile blockIdx.x:
// preload 16 B-fragments (bf16x8, exact-layout from prep), then per g:
// 2 ds_read + 2 MFMA. ~5024 waves (~5/SIMD), LDS 32 KB -> 5 blocks/CU.
// Epilogue: sign store + __ballot ambiguous (|v|<=0.25), wave-cooperative
// fp64 exact recompute (proven R9/R11), owner-lane overwrite.
// ---------------------------------------------------------------------------
__global__ __launch_bounds__(256, 4) void gemm_mfma(const uint16_t* __restrict__ bF,
                                                    const uint16_t* __restrict__ aHi,
                                                    const uint16_t* __restrict__ aLo,
                                                    const uint32_t* __restrict__ bitsT,
                                                    const double* __restrict__ sT64,
                                                    float* __restrict__ out) {
    __shared__ uint4 shA[2048];              // 32 KB: chunks 0..15 hi, 16..31 lo
    int tid  = (int)threadIdx.x;
    int lane = tid & 63;
    int wid  = tid >> 6;                     // nt = wid
    int mt   = blockIdx.y;                   // b-range mt*16..+15
    int t    = blockIdx.x;                   // d-tile (N=64)

    // --- cooperative A staging (chunk g = 1 KB = 64 lanes x 16 B) ---
    const uint4* AhU = (const uint4*)aHi;    // fragment (g,mt): base (g*8+mt)*64
    const uint4* AlU = (const uint4*)aLo;
    #pragma unroll
    for (int c = 0; c < 8; ++c) {
        int e = tid + 256 * c;               // 0..2047
        int chunk = e >> 6;                  // 0..31
        int l = e & 63;
        int g = chunk & 15;
        const uint4* src = (chunk < 16 ? AhU : AlU) + (size_t)(g * 8 + mt) * 64 + l;
        shA[e] = *src;
    }

    // --- per-wave B-fragment preload (independent of staging) ---
    int td = t * 4 + wid;
    int tdc = td < NTD ? td : NTD - 1;       // clamp (tail: nt>=1 of t=156 OOB)
    const bf16x8* BF = (const bf16x8*)bF;
    bf16x8 bfr[16];
    #pragma unroll
    for (int g = 0; g < 16; ++g)
        bfr[g] = BF[(size_t)(g * NTD + tdc) * 64 + lane];

    __syncthreads();                         // A staged

    f32x4 acc = (f32x4){0.f, 0.f, 0.f, 0.f};
    const bf16x8* shAv = (const bf16x8*)shA;
    #pragma unroll
    for (int g = 0; g < 16; ++g) {
        bf16x8 ah = shAv[g * 64 + lane];             // ds_read_b128
        bf16x8 al = shAv[(16 + g) * 64 + lane];
        acc = __builtin_amdgcn_mfma_f32_16x16x32_bf16(ah, bfr[g], acc, 0, 0, 0);
        acc = __builtin_amdgcn_mfma_f32_16x16x32_bf16(al, bfr[g], acc, 0, 0, 0);
    }

    // Epilogue. C/D layout: col = lane&15, row = (lane>>4)*4 + reg.
    int ln = lane & 15;
    int lh = lane >> 4;
    int d = t * 64 + wid * 16 + ln;
    bool valid = d < Dn;
    #pragma unroll
    for (int r = 0; r < 4; ++r) {
        int b = mt * 16 + lh * 4 + r;
        float v = acc[r];
        if (valid) out[(size_t)b * Dn + d] = v > 0.0f ? 1.0f : -1.0f;
        unsigned long long mask = __ballot(valid && fabsf(v) <= 0.25f);
        while (mask) {
            int l = __ffsll((long long)mask) - 1;
            mask &= mask - 1;
            int bl = mt * 16 + (l >> 4) * 4 + r;
            int dl = t * 64 + wid * 16 + (l & 15);
            const double* srow = sT64 + (size_t)bl * Wn;
            double a = 0.0;
            #pragma unroll
            for (int k = 0; k < 8; ++k) {
                int w = lane + 64 * k;
                uint32_t mw = bitsT[(size_t)dl * 16 + (w >> 5)];
                double s = srow[w];
                a += ((mw >> (w & 31)) & 1u) ? s : -s;
            }
            #pragma unroll
            for (int off = 32; off >= 1; off >>= 1)
                a += __shfl_xor(a, off, 64);
            if (lane == l)          // owner overwrites its own guess
                out[(size_t)bl * Dn + dl] = (a > 0.0) ? 1.0f : ((a < 0.0) ? -1.0f : 0.0f);
        }
    }
}

// ---------------------------------------------------------------------------
extern "C" void kernel_launch(void* const* d_in, const int* in_sizes, int n_in,
                              void* d_out, int out_size, void* d_ws, size_t ws_size,
                              hipStream_t stream) {
    const float* x   = (const float*)d_in[0];   // (128,128,512) f32
    const float* wts = (const float*)d_in[1];   // (512,10000)  f32, values +-1
    float* out = (float*)d_out;                 // (128,10000)  f32 signs
    char* ws = (char*)d_ws;

    // workspace layout (~11.67 MB total; R2 proved >= 11.93 MB available)
    double*   sT64  = (double*)(ws);                  // 128*512*8 = 524,288 B
    uint16_t* aHi   = (uint16_t*)(ws + 524288);       // 131,072 B
    uint16_t* aLo   = (uint16_t*)(ws + 655360);       // 131,072 B
    uint32_t* bitsT = (uint32_t*)(ws + 786432);       // 640,000 B
    uint16_t* bF    = (uint16_t*)(ws + 1426432);      // 16*625*512*2 = 10,240,000 B

    prep<<<1137, 256, 0, stream>>>(x, wts, sT64, aHi, aLo, bitsT, bF);
    gemm_mfma<<<dim3(157, 8), 256, 0, stream>>>(bF, aHi, aLo, bitsT, sT64, out);
}